// Round 3
// baseline (328.605 us; speedup 1.0000x reference)
//
#include <hip/hip_runtime.h>
#include <hip/hip_fp16.h>

// GrCNetConvOnly: out[b] = sum_{c,d} relu(wa[c]*h[b,d] + wb[c]*r[b,d] + wc[c]*t[b,d] + cb[c]) * fcw[c*D+d] + fcb
// B=16384, D=400, C=50.
// Packed-f16 math (v_pk_fma_f16 / v_pk_max_f16: 2 d's per op) halves the f32 VALU floor.
// Block = 8 batch elems, 4 waves; wave w owns d-pair slice [64w, 64w+63].
// h/r/t slices hoisted to registers; conv params staged in LDS as duplicated half2.
// half2 accumulator flushed to f32 every ~17 c's (3 chunks) to bound fp16 rounding walk.

constexpr int D = 400;
constexpr int C = 50;
constexpr int PAIRS = D / 2;   // 200 half2 pairs per row
constexpr int BPB = 8;         // batch elems per block

// relu on packed fp16: ROCm 7.2 lacks __hmax2; v_pk_max_f16 with inline-const 0.
static __device__ __forceinline__ __half2 relu2(__half2 x) {
    union { __half2 h; unsigned int u; } in, out;
    in.h = x;
    asm("v_pk_max_f16 %0, %1, 0" : "=v"(out.u) : "v"(in.u));
    return out.h;
}

__global__ __launch_bounds__(256, 4) void grcnet_fused_f16(
    const float* __restrict__ entity_emb,
    const float* __restrict__ relation_emb,
    const float* __restrict__ conv_w,       // (C,1,1,3)
    const float* __restrict__ conv_b,       // (C)
    const float* __restrict__ fc_w,         // (C*D)
    const float* __restrict__ fc_b,         // (1)
    const int*   __restrict__ batch_inputs, // (B,3)
    float* __restrict__ out,                // (B)
    int nB)
{
    __shared__ __half2 conv_lds[C][4];      // [c] = {wa,wa},{wb,wb},{wc,wc},{cb,cb}
    __shared__ float  partials[4][BPB];

    const int tid  = threadIdx.x;
    const int lane = tid & 63;
    const int wv   = tid >> 6;              // d-slice index 0..3
    const int b0   = blockIdx.x * BPB;
    if (b0 >= nB) return;                   // uniform across block

    // --- stage conv params into LDS as duplicated half2 (threads 0..C-1) ---
    if (tid < C) {
        const float wa = conv_w[3*tid+0], wb = conv_w[3*tid+1], wc = conv_w[3*tid+2];
        const float cb = conv_b[tid];
        conv_lds[tid][0] = __floats2half2_rn(wa, wa);
        conv_lds[tid][1] = __floats2half2_rn(wb, wb);
        conv_lds[tid][2] = __floats2half2_rn(wc, wc);
        conv_lds[tid][3] = __floats2half2_rn(cb, cb);
    }

    // --- this lane's d-pair ---
    const int  p   = wv * 64 + lane;        // pair index 0..255; valid < 200
    const bool act = (p < PAIRS);
    const int  pc  = act ? p : 0;           // clamped (loads stay in-bounds)

    // --- hoist all h/r/t slices into registers (24 independent float2 loads) ---
    __half2 hh[BPB], rr[BPB], tt[BPB];
    const int* bi = batch_inputs + b0 * 3;  // uniform -> s_load
    #pragma unroll
    for (int b = 0; b < BPB; ++b) {
        const int hi = bi[3*b+0], ri = bi[3*b+1], ti = bi[3*b+2];
        const float2 hv = *(const float2*)(entity_emb   + (size_t)hi * D + 2*pc);
        const float2 rv = *(const float2*)(relation_emb + (size_t)ri * D + 2*pc);
        const float2 tv = *(const float2*)(entity_emb   + (size_t)ti * D + 2*pc);
        hh[b] = __floats2half2_rn(hv.x, hv.y);
        rr[b] = __floats2half2_rn(rv.x, rv.y);
        tt[b] = __floats2half2_rn(tv.x, tv.y);
    }

    __syncthreads();                        // conv_lds ready

    const __half2 zero2 = __floats2half2_rn(0.f, 0.f);
    float2 accf[BPB];
    #pragma unroll
    for (int b = 0; b < BPB; ++b) accf[b] = make_float2(0.f, 0.f);

    const float2* fcp = (const float2*)fc_w;   // fc_w[c*D + 2p] == fcp[c*PAIRS + p]

    // chunked c-loop: fp16 inner accumulation, f32 flush per chunk
    #define CHUNK(C0, C1)                                                        \
    {                                                                            \
        __half2 la[BPB];                                                         \
        _Pragma("unroll")                                                        \
        for (int b = 0; b < BPB; ++b) la[b] = zero2;                             \
        _Pragma("unroll")                                                        \
        for (int c = (C0); c < (C1); ++c) {                                      \
            const __half2 wa = conv_lds[c][0];                                   \
            const __half2 wb = conv_lds[c][1];                                   \
            const __half2 wc = conv_lds[c][2];                                   \
            const __half2 cb = conv_lds[c][3];                                   \
            float2 fv = fcp[c * PAIRS + pc];                                     \
            if (!act) { fv.x = 0.f; fv.y = 0.f; }                                \
            const __half2 f2 = __floats2half2_rn(fv.x, fv.y);                    \
            _Pragma("unroll")                                                    \
            for (int b = 0; b < BPB; ++b) {                                      \
                __half2 s = __hfma2(hh[b], wa,                                   \
                              __hfma2(rr[b], wb, __hfma2(tt[b], wc, cb)));       \
                la[b] = __hfma2(relu2(s), f2, la[b]);                            \
            }                                                                    \
        }                                                                        \
        _Pragma("unroll")                                                        \
        for (int b = 0; b < BPB; ++b) {                                          \
            const float2 lf = __half22float2(la[b]);                             \
            accf[b].x += lf.x; accf[b].y += lf.y;                                \
        }                                                                        \
    }

    CHUNK(0, 17)
    CHUNK(17, 34)
    CHUNK(34, 50)
    #undef CHUNK

    // --- reduce: f32 wave shuffle, cross-wave via LDS ---
    #pragma unroll
    for (int b = 0; b < BPB; ++b) {
        float a = accf[b].x + accf[b].y;
        #pragma unroll
        for (int off = 32; off; off >>= 1) a += __shfl_xor(a, off);
        if (lane == 0) partials[wv][b] = a;
    }
    __syncthreads();

    if (tid < BPB) {
        const float fb = fc_b[0];
        out[b0 + tid] = partials[0][tid] + partials[1][tid]
                      + partials[2][tid] + partials[3][tid] + fb;
    }
}

extern "C" void kernel_launch(void* const* d_in, const int* in_sizes, int n_in,
                              void* d_out, int out_size, void* d_ws, size_t ws_size,
                              hipStream_t stream) {
    const float* entity_emb   = (const float*)d_in[0];
    const float* relation_emb = (const float*)d_in[1];
    const float* conv_w       = (const float*)d_in[2];
    const float* conv_b       = (const float*)d_in[3];
    const float* fc_w         = (const float*)d_in[4];
    const float* fc_b         = (const float*)d_in[5];
    const int*   batch_inputs = (const int*)d_in[6];
    float* out = (float*)d_out;

    const int nB = in_sizes[6] / 3;          // 16384
    const int blocks = (nB + BPB - 1) / BPB; // 2048
    grcnet_fused_f16<<<blocks, 256, 0, stream>>>(
        entity_emb, relation_emb, conv_w, conv_b, fc_w, fc_b, batch_inputs, out, nB);
}

// Round 4
// 59.535 us; speedup vs baseline: 5.5195x; 5.5195x over previous
//
#include <hip/hip_runtime.h>

// GrCNetConvOnly: out[b] = sum_{c,d} relu(wa[c]*h[b,d] + wb[c]*r[b,d] + wc[c]*t[b,d] + cb[c]) * fcw[c*D+d] + fcb
// B=16384, D=400, C=50. f32 VALU path (R3's fp16 spilled to scratch: 614MB WRITE_SIZE).
// Block = 512 thr = 8 waves = 4 b-groups x 2 c-halves. Each wave: 4 b's, 25 c's, lane=d.
// The c-split doubles resident waves vs R1 (32/CU = 8/SIMD) for latency hiding; paired
// waves share h/r/t rows (L1 hits). conv params staged once in LDS as float4 per c.

constexpr int D = 400;
constexpr int C = 50;

__global__ __launch_bounds__(512, 8) void grcnet_fused_f32(
    const float* __restrict__ entity_emb,
    const float* __restrict__ relation_emb,
    const float* __restrict__ conv_w,       // (C,1,1,3)
    const float* __restrict__ conv_b,       // (C)
    const float* __restrict__ fc_w,         // (C*D)
    const float* __restrict__ fc_b,         // (1)
    const int*   __restrict__ batch_inputs, // (B,3)
    float* __restrict__ out,                // (B)
    int nB)
{
    __shared__ float4 conv_lds[C];          // (wa, wb, wc, cb) per c
    __shared__ float  partials[2][4][4];    // [c-half][group][b]

    const int tid  = threadIdx.x;
    const int lane = tid & 63;
    const int wv   = tid >> 6;              // 0..7
    const int grp  = wv >> 1;               // b-group 0..3
    const int half = wv & 1;                // c-half 0..1
    const int b0   = blockIdx.x * 16;       // 16 b per block
    if (b0 >= nB) return;

    if (tid < C) {
        conv_lds[tid] = make_float4(conv_w[3*tid+0], conv_w[3*tid+1],
                                    conv_w[3*tid+2], conv_b[tid]);
    }
    __syncthreads();

    // wave-uniform batch base -> s_load index fetches
    const int bbase = __builtin_amdgcn_readfirstlane(b0 + 4 * grp);
    const int* bi = batch_inputs + 3 * bbase;
    const int h0i = bi[0], r0i = bi[1], t0i = bi[2];
    const int h1i = bi[3], r1i = bi[4], t1i = bi[5];
    const int h2i = bi[6], r2i = bi[7], t2i = bi[8];
    const int h3i = bi[9], r3i = bi[10], t3i = bi[11];

    const float* eh0 = entity_emb   + (size_t)h0i * D;
    const float* er0 = relation_emb + (size_t)r0i * D;
    const float* et0 = entity_emb   + (size_t)t0i * D;
    const float* eh1 = entity_emb   + (size_t)h1i * D;
    const float* er1 = relation_emb + (size_t)r1i * D;
    const float* et1 = entity_emb   + (size_t)t1i * D;
    const float* eh2 = entity_emb   + (size_t)h2i * D;
    const float* er2 = relation_emb + (size_t)r2i * D;
    const float* et2 = entity_emb   + (size_t)t2i * D;
    const float* eh3 = entity_emb   + (size_t)h3i * D;
    const float* er3 = relation_emb + (size_t)r3i * D;
    const float* et3 = entity_emb   + (size_t)t3i * D;

    const int c0 = half * 25;               // this wave's c-range [c0, c0+25)

    float acc0 = 0.f, acc1 = 0.f, acc2 = 0.f, acc3 = 0.f;

    for (int i = 0; i < 7; ++i) {
        const int d = lane + 64 * i;
        const bool act = (d < D);
        const int dc = act ? d : 0;         // clamped: loads stay in-bounds

        const float h0 = eh0[dc], r0 = er0[dc], t0 = et0[dc];
        const float h1 = eh1[dc], r1 = er1[dc], t1 = et1[dc];
        const float h2 = eh2[dc], r2 = er2[dc], t2 = et2[dc];
        const float h3 = eh3[dc], r3 = er3[dc], t3 = et3[dc];

        float la0 = 0.f, la1 = 0.f, la2 = 0.f, la3 = 0.f;
        const float* fp = fc_w + dc;

        #pragma unroll 5
        for (int c = c0; c < c0 + 25; ++c) {
            const float4 cw = conv_lds[c];  // broadcast ds_read_b128
            const float f  = fp[c * D];

            float s0 = fmaf(cw.x, h0, fmaf(cw.y, r0, fmaf(cw.z, t0, cw.w)));
            float s1 = fmaf(cw.x, h1, fmaf(cw.y, r1, fmaf(cw.z, t1, cw.w)));
            float s2 = fmaf(cw.x, h2, fmaf(cw.y, r2, fmaf(cw.z, t2, cw.w)));
            float s3 = fmaf(cw.x, h3, fmaf(cw.y, r3, fmaf(cw.z, t3, cw.w)));
            la0 = fmaf(fmaxf(s0, 0.f), f, la0);
            la1 = fmaf(fmaxf(s1, 0.f), f, la1);
            la2 = fmaf(fmaxf(s2, 0.f), f, la2);
            la3 = fmaf(fmaxf(s3, 0.f), f, la3);
        }
        if (act) { acc0 += la0; acc1 += la1; acc2 += la2; acc3 += la3; }
    }

    // wave-wide sum
    #pragma unroll
    for (int off = 32; off > 0; off >>= 1) {
        acc0 += __shfl_xor(acc0, off);
        acc1 += __shfl_xor(acc1, off);
        acc2 += __shfl_xor(acc2, off);
        acc3 += __shfl_xor(acc3, off);
    }
    if (lane == 0) {
        partials[half][grp][0] = acc0;
        partials[half][grp][1] = acc1;
        partials[half][grp][2] = acc2;
        partials[half][grp][3] = acc3;
    }
    __syncthreads();

    if (tid < 16) {
        const int g = tid >> 2, j = tid & 3;
        out[b0 + 4*g + j] = partials[0][g][j] + partials[1][g][j] + fc_b[0];
    }
}

extern "C" void kernel_launch(void* const* d_in, const int* in_sizes, int n_in,
                              void* d_out, int out_size, void* d_ws, size_t ws_size,
                              hipStream_t stream) {
    const float* entity_emb   = (const float*)d_in[0];
    const float* relation_emb = (const float*)d_in[1];
    const float* conv_w       = (const float*)d_in[2];
    const float* conv_b       = (const float*)d_in[3];
    const float* fc_w         = (const float*)d_in[4];
    const float* fc_b         = (const float*)d_in[5];
    const int*   batch_inputs = (const int*)d_in[6];
    float* out = (float*)d_out;

    const int nB = in_sizes[6] / 3;          // 16384
    const int blocks = (nB + 15) / 16;       // 1024
    grcnet_fused_f32<<<blocks, 512, 0, stream>>>(
        entity_emb, relation_emb, conv_w, conv_b, fc_w, fc_b, batch_inputs, out, nB);
}